// Round 1
// baseline (2051.521 us; speedup 1.0000x reference)
//
#include <hip/hip_runtime.h>

using f32x4  = __attribute__((ext_vector_type(4))) float;
using short8 = __attribute__((ext_vector_type(8))) short;

__device__ __forceinline__ unsigned short f2bf(float f) {
  unsigned u = __builtin_bit_cast(unsigned, f);
  u = (u + 0x7FFFu + ((u >> 16) & 1u)) >> 16;
  return (unsigned short)u;
}
__device__ __forceinline__ float bf2f(unsigned short s) {
  return __builtin_bit_cast(float, ((unsigned)s) << 16);
}

// ---------------- K0: transpose points (B,64,4096)->bf16 (B,4096,64); xyz -> float4(x,y,z,|p|^2)
__global__ __launch_bounds__(256) void k_prep(const float* __restrict__ points,
                                              const float* __restrict__ xyz,
                                              unsigned short* __restrict__ pT,
                                              float4* __restrict__ xyz4) {
  __shared__ float tile[64][65];
  int t = threadIdx.x, blk = blockIdx.x;
  int b = blk >> 6, n0 = (blk & 63) << 6;
#pragma unroll
  for (int p = 0; p < 16; ++p) {
    int c = p * 4 + (t >> 6);
    tile[c][t & 63] = points[(size_t)b * 262144 + (size_t)c * 4096 + n0 + (t & 63)];
  }
  if (t < 64) {
    int n = n0 + t;
    float x = xyz[(size_t)b * 12288 + n];
    float y = xyz[(size_t)b * 12288 + 4096 + n];
    float z = xyz[(size_t)b * 12288 + 8192 + n];
    float ps = __fadd_rn(__fadd_rn(__fmul_rn(x, x), __fmul_rn(y, y)), __fmul_rn(z, z));
    xyz4[(size_t)b * 4096 + n] = make_float4(x, y, z, ps);
  }
  __syncthreads();
  int nl = t >> 2, coff = (t & 3) * 16;
  unsigned v[8];
#pragma unroll
  for (int j = 0; j < 8; ++j) {
    unsigned lo = f2bf(tile[coff + 2 * j][nl]);
    unsigned hi = f2bf(tile[coff + 2 * j + 1][nl]);
    v[j] = lo | (hi << 16);
  }
  uint4* dst = reinterpret_cast<uint4*>(pT + ((size_t)b * 4096 + n0 + nl) * 64 + coff);
  dst[0] = make_uint4(v[0], v[1], v[2], v[3]);
  dst[1] = make_uint4(v[4], v[5], v[6], v[7]);
}

// ---------------- FPS: 1 block/batch, bitwise-exact f32 chain (no FMA contraction)
__global__ __launch_bounds__(512) void k_fps(const float* __restrict__ xyz,
                                             float* __restrict__ out0,
                                             float* __restrict__ out2,
                                             int* __restrict__ fpsidx,
                                             float4* __restrict__ nq4) {
  __shared__ float sxs[4096], sys[4096], szs[4096];
  __shared__ float redv[2][8];
  __shared__ int   redi[2][8];
  int b = blockIdx.x, t = threadIdx.x;
  float px[8], py[8], pz[8], dist[8];
#pragma unroll
  for (int j = 0; j < 8; ++j) {
    int n = t + (j << 9);
    float x = xyz[(size_t)b * 12288 + n];
    float y = xyz[(size_t)b * 12288 + 4096 + n];
    float z = xyz[(size_t)b * 12288 + 8192 + n];
    px[j] = x; py[j] = y; pz[j] = z; dist[j] = 1e10f;
    sxs[n] = x; sys[n] = y; szs[n] = z;
  }
  __syncthreads();
  int lane = t & 63, wid = t >> 6;
  int far = 0, fh0 = 0, fh1 = 0;
  float cx = sxs[0], cy = sys[0], cz = szs[0];
  for (int it = 0; it < 1024; ++it) {
    if (t == (it & 511)) { if (it < 512) fh0 = far; else fh1 = far; }
    float bv = -1.f; int bi = 0;
#pragma unroll
    for (int j = 0; j < 8; ++j) {
      float dx = __fsub_rn(px[j], cx);
      float dy = __fsub_rn(py[j], cy);
      float dz = __fsub_rn(pz[j], cz);
      float d  = __fadd_rn(__fadd_rn(__fmul_rn(dx, dx), __fmul_rn(dy, dy)), __fmul_rn(dz, dz));
      float nd = fminf(dist[j], d);
      dist[j] = nd;
      if (nd > bv) { bv = nd; bi = t + (j << 9); }   // ascending idx -> first-max on ties
    }
#pragma unroll
    for (int off = 32; off; off >>= 1) {
      float ov = __shfl_xor(bv, off);
      int   oi = __shfl_xor(bi, off);
      if (ov > bv || (ov == bv && oi < bi)) { bv = ov; bi = oi; }
    }
    int pb = it & 1;
    if (lane == 0) { redv[pb][wid] = bv; redi[pb][wid] = bi; }
    __syncthreads();
    bv = redv[pb][0]; bi = redi[pb][0];
#pragma unroll
    for (int w = 1; w < 8; ++w) {
      float ov = redv[pb][w]; int oi = redi[pb][w];
      if (ov > bv || (ov == bv && oi < bi)) { bv = ov; bi = oi; }
    }
    far = bi;
    cx = sxs[far]; cy = sys[far]; cz = szs[far];
  }
  __syncthreads();
#pragma unroll
  for (int h = 0; h < 2; ++h) {
    int k = t + (h << 9);
    int fr = h ? fh1 : fh0;
    float x = sxs[fr], y = sys[fr], z = szs[fr];
    fpsidx[(b << 10) + k] = fr;
    out2[(b << 10) + k] = (float)fr;
    out0[(size_t)b * 3072 + k]        = x;
    out0[(size_t)b * 3072 + 1024 + k] = y;
    out0[(size_t)b * 3072 + 2048 + k] = z;
    float ps = __fadd_rn(__fadd_rn(__fmul_rn(x, x), __fmul_rn(y, y)), __fmul_rn(z, z));
    nq4[(b << 10) + k] = make_float4(x, y, z, ps);
  }
}

// ---------------- Ball query: wave/query; compact in-ball; 32x stable (d,idx) extraction
#define BCAP 384
__global__ __launch_bounds__(256) void k_ball(const float4* __restrict__ xyz4,
                                              const int* __restrict__ fpsidx,
                                              int* __restrict__ ballidx) {
  __shared__ float sxs[4096], sys[4096], szs[4096];
  __shared__ float sd[4][BCAP];
  __shared__ int   si[4][BCAP];
  int t = threadIdx.x, blk = blockIdx.x;
  int b = blk >> 6;
  for (int i = t; i < 4096; i += 256) {
    float4 p = xyz4[(size_t)b * 4096 + i];
    sxs[i] = p.x; sys[i] = p.y; szs[i] = p.z;
  }
  __syncthreads();
  int lane = t & 63, wid = t >> 6;
  for (int r = 0; r < 4; ++r) {
    int q = blk * 16 + r * 4 + wid;
    int qi = fpsidx[q];
    float qx = sxs[qi], qy = sys[qi], qz = szs[qi];
    float qs = __fadd_rn(__fadd_rn(__fmul_rn(qx, qx), __fmul_rn(qy, qy)), __fmul_rn(qz, qz));
    int cnt = 0;
    for (int i = 0; i < 64; ++i) {
      int n = (i << 6) + lane;
      float x = sxs[n], y = sys[n], z = szs[n];
      float ps  = __fadd_rn(__fadd_rn(__fmul_rn(x, x), __fmul_rn(y, y)), __fmul_rn(z, z));
      float dot = __fadd_rn(__fadd_rn(__fmul_rn(qx, x), __fmul_rn(qy, y)), __fmul_rn(qz, z));
      float d   = __fadd_rn(__fadd_rn(__fmul_rn(-2.f, dot), qs), ps);   // exact np expansion
      bool in = (d <= 0.04f);   // matches  !(d > f32(0.04))
      unsigned long long m = __ballot(in);
      int pos = cnt + (int)__popcll(m & ((1ull << lane) - 1ull));
      if (in && pos < BCAP) { sd[wid][pos] = d; si[wid][pos] = n; }
      cnt += (int)__popcll(m);
    }
    if (cnt > BCAP) cnt = BCAP;
    float ld[6]; int li[6];
#pragma unroll
    for (int u = 0; u < 6; ++u) {
      int slot = lane + (u << 6);
      bool v = slot < cnt;
      ld[u] = v ? sd[wid][slot] : 1e30f;
      li[u] = v ? si[wid][slot] : 0x7fffffff;
    }
    float pd = -1e30f; int pi = -1; int firstI = 0;
#pragma unroll 1
    for (int rr = 0; rr < 32; ++rr) {
      float bd = 1e30f; int bi = 0x7fffffff;
#pragma unroll
      for (int u = 0; u < 6; ++u) {
        bool gt = (ld[u] > pd) || (ld[u] == pd && li[u] > pi);
        bool lt = (ld[u] < bd) || (ld[u] == bd && li[u] < bi);
        if (gt && lt) { bd = ld[u]; bi = li[u]; }
      }
#pragma unroll
      for (int off = 32; off; off >>= 1) {
        float od = __shfl_xor(bd, off);
        int   oi = __shfl_xor(bi, off);
        if (od < bd || (od == bd && oi < bi)) { bd = od; bi = oi; }
      }
      if (rr == 0) firstI = bi;
      int outv = (bd < 1e30f) ? bi : firstI;   // pad with first (== idx[...,0]) when < 32 in-ball
      if (lane == 0) ballidx[(size_t)q * 32 + rr] = outv;
      if (bd < 1e30f) { pd = bd; pi = bi; }
    }
  }
}

// ---------------- Layer1: gather + bf16 MFMA GEMM (K=96 padded), store x1 bf16 + stats partials
__global__ __launch_bounds__(256) void k_gemm1(const unsigned short* __restrict__ pT,
    const float4* __restrict__ xyz4, const float4* __restrict__ nq4,
    const int* __restrict__ bidx, const float* __restrict__ wgt,
    const float* __restrict__ bia, unsigned short* __restrict__ xbuf,
    float* __restrict__ part) {
  __shared__ unsigned short A[64][104];
  __shared__ unsigned short W[64][104];
  __shared__ float sred[4][2][64];
  int t = threadIdx.x, blk = blockIdx.x;
  int b = blk >> 9;
  for (int e = t; e < 64 * 96; e += 256) {
    int o = e / 96, k = e - o * 96;
    // input channel reorder: A cols [0..63]=points, [64..66]=xyz-norm, rest zero
    float v = (k < 64) ? wgt[o * 67 + 3 + k] : ((k < 67) ? wgt[o * 67 + (k - 64)] : 0.f);
    W[o][k] = f2bf(v);
  }
  {
    int rt = t >> 2, sub = t & 3;
    int q = (blk << 1) + (rt >> 5);
    int n = bidx[(size_t)q * 32 + (rt & 31)];
    const uint4* src = reinterpret_cast<const uint4*>(pT + ((size_t)(b * 4096 + n)) * 64 + sub * 16);
    uint4 v0 = src[0], v1 = src[1];
    *reinterpret_cast<uint4*>(&A[rt][sub * 16])     = v0;
    *reinterpret_cast<uint4*>(&A[rt][sub * 16 + 8]) = v1;
    if (sub == 0) {
      float4 P = xyz4[(size_t)b * 4096 + n];
      float4 Qc = nq4[q];
      A[rt][64] = f2bf(__fsub_rn(P.x, Qc.x));
      A[rt][65] = f2bf(__fsub_rn(P.y, Qc.y));
      A[rt][66] = f2bf(__fsub_rn(P.z, Qc.z));
    } else if (sub == 1) {
#pragma unroll
      for (int k = 67; k < 96; ++k) A[rt][k] = 0;
    }
  }
  __syncthreads();
  int lane = t & 63, wid = t >> 6;
  int cl = lane & 15, rg = lane >> 4;
  int rowb = (wid << 4) + cl, ko = rg << 3;
  f32x4 acc[4] = {};
#pragma unroll
  for (int ks = 0; ks < 96; ks += 32) {
    short8 a = *reinterpret_cast<const short8*>(&A[rowb][ks + ko]);
#pragma unroll
    for (int nt = 0; nt < 4; ++nt) {
      short8 bb = *reinterpret_cast<const short8*>(&W[nt * 16 + cl][ks + ko]);
      acc[nt] = __builtin_amdgcn_mfma_f32_16x16x32_bf16(a, bb, acc[nt], 0, 0, 0);
    }
  }
#pragma unroll
  for (int nt = 0; nt < 4; ++nt) {
    int ch = nt * 16 + cl;
    float bv = bia[ch];
    float v0 = acc[nt][0] + bv, v1 = acc[nt][1] + bv, v2 = acc[nt][2] + bv, v3 = acc[nt][3] + bv;
    size_t gr = (size_t)blk * 64 + (wid << 4) + (rg << 2);
    xbuf[(gr + 0) * 64 + ch] = f2bf(v0);
    xbuf[(gr + 1) * 64 + ch] = f2bf(v1);
    xbuf[(gr + 2) * 64 + ch] = f2bf(v2);
    xbuf[(gr + 3) * 64 + ch] = f2bf(v3);
    float s1 = (v0 + v1) + (v2 + v3);
    float s2 = (v0 * v0 + v1 * v1) + (v2 * v2 + v3 * v3);
    s1 += __shfl_xor(s1, 16); s1 += __shfl_xor(s1, 32);
    s2 += __shfl_xor(s2, 16); s2 += __shfl_xor(s2, 32);
    if (rg == 0) { sred[wid][0][ch] = s1; sred[wid][1][ch] = s2; }
  }
  __syncthreads();
  if (t < 128) {
    int ch = t & 63, wh = t >> 6;
    float v = sred[0][wh][ch] + sred[1][wh][ch] + sred[2][wh][ch] + sred[3][wh][ch];
    part[(size_t)blk * 128 + ch * 2 + wh] = v;
  }
}

// ---------------- stats partial reduce -> folded BN scale/shift
__global__ __launch_bounds__(256) void k_red(const float* __restrict__ part, int nblk, int nch,
    const float* __restrict__ gamma, const float* __restrict__ beta,
    float* __restrict__ scale, float* __restrict__ shift) {
  int c = blockIdx.x, t = threadIdx.x;
  int stride = 2 * nch;
  float s1 = 0.f, s2 = 0.f;
  for (int i = t; i < nblk; i += 256) {
    s1 += part[(size_t)i * stride + 2 * c];
    s2 += part[(size_t)i * stride + 2 * c + 1];
  }
  __shared__ float r1[256], r2[256];
  r1[t] = s1; r2[t] = s2;
  __syncthreads();
  for (int o = 128; o > 0; o >>= 1) {
    if (t < o) { r1[t] += r1[t + o]; r2[t] += r2[t + o]; }
    __syncthreads();
  }
  if (t == 0) {
    const float N = 524288.f;
    float mu = r1[0] / N;
    float var = r2[0] / N - mu * mu;
    float a = gamma[c] / sqrtf(var + 1e-5f);
    scale[c] = a;
    shift[c] = beta[c] - a * mu;
  }
}

// ---------------- Layer2: read x1 (bf16) -> BN1+ReLU -> GEMM -> x2 in-place + stats
__global__ __launch_bounds__(256) void k_gemm2(unsigned short* __restrict__ xbuf,
    const float* __restrict__ wgt, const float* __restrict__ bia,
    const float* __restrict__ sc, const float* __restrict__ sh,
    float* __restrict__ part) {
  __shared__ unsigned short A[64][72];
  __shared__ unsigned short W[64][72];
  __shared__ float ssc[64], ssh[64];
  __shared__ float sred[4][2][64];
  int t = threadIdx.x, blk = blockIdx.x;
  if (t < 64) { ssc[t] = sc[t]; ssh[t] = sh[t]; }
  __syncthreads();
  for (int e = t; e < 4096; e += 256) {
    int o = e >> 6, k = e & 63;
    W[o][k] = f2bf(wgt[(size_t)o * 64 + k]);
  }
  {
    int rt = t >> 2, sub = t & 3;
    size_t gr = (size_t)blk * 64 + rt;
    const uint4* src = reinterpret_cast<const uint4*>(xbuf + gr * 64 + sub * 16);
    uint4 v0 = src[0], v1 = src[1];
    unsigned wv[8] = {v0.x, v0.y, v0.z, v0.w, v1.x, v1.y, v1.z, v1.w};
#pragma unroll
    for (int j = 0; j < 8; ++j) {
      int c = sub * 16 + 2 * j;
      float x0 = bf2f((unsigned short)(wv[j] & 0xffffu));
      float x1 = bf2f((unsigned short)(wv[j] >> 16));
      A[rt][c]     = f2bf(fmaxf(0.f, ssc[c] * x0 + ssh[c]));
      A[rt][c + 1] = f2bf(fmaxf(0.f, ssc[c + 1] * x1 + ssh[c + 1]));
    }
  }
  __syncthreads();
  int lane = t & 63, wid = t >> 6;
  int cl = lane & 15, rg = lane >> 4;
  int rowb = (wid << 4) + cl, ko = rg << 3;
  f32x4 acc[4] = {};
#pragma unroll
  for (int ks = 0; ks < 64; ks += 32) {
    short8 a = *reinterpret_cast<const short8*>(&A[rowb][ks + ko]);
#pragma unroll
    for (int nt = 0; nt < 4; ++nt) {
      short8 bb = *reinterpret_cast<const short8*>(&W[nt * 16 + cl][ks + ko]);
      acc[nt] = __builtin_amdgcn_mfma_f32_16x16x32_bf16(a, bb, acc[nt], 0, 0, 0);
    }
  }
#pragma unroll
  for (int nt = 0; nt < 4; ++nt) {
    int ch = nt * 16 + cl;
    float bv = bia[ch];
    float v0 = acc[nt][0] + bv, v1 = acc[nt][1] + bv, v2 = acc[nt][2] + bv, v3 = acc[nt][3] + bv;
    size_t gr = (size_t)blk * 64 + (wid << 4) + (rg << 2);
    xbuf[(gr + 0) * 64 + ch] = f2bf(v0);
    xbuf[(gr + 1) * 64 + ch] = f2bf(v1);
    xbuf[(gr + 2) * 64 + ch] = f2bf(v2);
    xbuf[(gr + 3) * 64 + ch] = f2bf(v3);
    float s1 = (v0 + v1) + (v2 + v3);
    float s2 = (v0 * v0 + v1 * v1) + (v2 * v2 + v3 * v3);
    s1 += __shfl_xor(s1, 16); s1 += __shfl_xor(s1, 32);
    s2 += __shfl_xor(s2, 16); s2 += __shfl_xor(s2, 32);
    if (rg == 0) { sred[wid][0][ch] = s1; sred[wid][1][ch] = s2; }
  }
  __syncthreads();
  if (t < 128) {
    int ch = t & 63, wh = t >> 6;
    float v = sred[0][wh][ch] + sred[1][wh][ch] + sred[2][wh][ch] + sred[3][wh][ch];
    part[(size_t)blk * 128 + ch * 2 + wh] = v;
  }
}

// ---------------- Layer3 (N=128): STATS pass, then FINAL pass (recompute + BN3+ReLU + k-max)
template<bool FINAL>
__global__ __launch_bounds__(256) void k_gemm3(const unsigned short* __restrict__ xbuf,
    const float* __restrict__ wgt, const float* __restrict__ bia,
    const float* __restrict__ sc2, const float* __restrict__ sh2,
    const float* __restrict__ sc3, const float* __restrict__ sh3,
    float* __restrict__ part, float* __restrict__ kmaxb) {
  __shared__ unsigned short A[64][72];
  __shared__ unsigned short W[128][72];
  __shared__ float ssc[64], ssh[64];
  __shared__ float s3c[128], s3h[128];
  __shared__ float sred[4][2][128];
  int t = threadIdx.x, blk = blockIdx.x;
  if (t < 64) { ssc[t] = sc2[t]; ssh[t] = sh2[t]; }
  if (FINAL && t >= 128) { s3c[t - 128] = sc3[t - 128]; s3h[t - 128] = sh3[t - 128]; }
  __syncthreads();
  for (int e = t; e < 8192; e += 256) {
    int o = e >> 6, k = e & 63;
    W[o][k] = f2bf(wgt[(size_t)o * 64 + k]);
  }
  {
    int rt = t >> 2, sub = t & 3;
    size_t gr = (size_t)blk * 64 + rt;
    const uint4* src = reinterpret_cast<const uint4*>(xbuf + gr * 64 + sub * 16);
    uint4 v0 = src[0], v1 = src[1];
    unsigned wv[8] = {v0.x, v0.y, v0.z, v0.w, v1.x, v1.y, v1.z, v1.w};
#pragma unroll
    for (int j = 0; j < 8; ++j) {
      int c = sub * 16 + 2 * j;
      float x0 = bf2f((unsigned short)(wv[j] & 0xffffu));
      float x1 = bf2f((unsigned short)(wv[j] >> 16));
      A[rt][c]     = f2bf(fmaxf(0.f, ssc[c] * x0 + ssh[c]));
      A[rt][c + 1] = f2bf(fmaxf(0.f, ssc[c + 1] * x1 + ssh[c + 1]));
    }
  }
  __syncthreads();
  int lane = t & 63, wid = t >> 6;
  int cl = lane & 15, rg = lane >> 4;
  int rowb = (wid << 4) + cl, ko = rg << 3;
  f32x4 acc[8] = {};
#pragma unroll
  for (int ks = 0; ks < 64; ks += 32) {
    short8 a = *reinterpret_cast<const short8*>(&A[rowb][ks + ko]);
#pragma unroll
    for (int nt = 0; nt < 8; ++nt) {
      short8 bb = *reinterpret_cast<const short8*>(&W[nt * 16 + cl][ks + ko]);
      acc[nt] = __builtin_amdgcn_mfma_f32_16x16x32_bf16(a, bb, acc[nt], 0, 0, 0);
    }
  }
  if (!FINAL) {
#pragma unroll
    for (int nt = 0; nt < 8; ++nt) {
      int ch = nt * 16 + cl;
      float bv = bia[ch];
      float v0 = acc[nt][0] + bv, v1 = acc[nt][1] + bv, v2 = acc[nt][2] + bv, v3 = acc[nt][3] + bv;
      float s1 = (v0 + v1) + (v2 + v3);
      float s2 = (v0 * v0 + v1 * v1) + (v2 * v2 + v3 * v3);
      s1 += __shfl_xor(s1, 16); s1 += __shfl_xor(s1, 32);
      s2 += __shfl_xor(s2, 16); s2 += __shfl_xor(s2, 32);
      if (rg == 0) { sred[wid][0][ch] = s1; sred[wid][1][ch] = s2; }
    }
    __syncthreads();
    {
      int ch = t & 127, wh = t >> 7;
      float v = sred[0][wh][ch] + sred[1][wh][ch] + sred[2][wh][ch] + sred[3][wh][ch];
      part[(size_t)blk * 256 + ch * 2 + wh] = v;
    }
  } else {
#pragma unroll
    for (int nt = 0; nt < 8; ++nt) {
      int ch = nt * 16 + cl;
      float bv = bia[ch];
      float a0 = fmaxf(0.f, s3c[ch] * (acc[nt][0] + bv) + s3h[ch]);
      float a1 = fmaxf(0.f, s3c[ch] * (acc[nt][1] + bv) + s3h[ch]);
      float a2 = fmaxf(0.f, s3c[ch] * (acc[nt][2] + bv) + s3h[ch]);
      float a3 = fmaxf(0.f, s3c[ch] * (acc[nt][3] + bv) + s3h[ch]);
      float m = fmaxf(fmaxf(a0, a1), fmaxf(a2, a3));
      m = fmaxf(m, __shfl_xor(m, 16));
      m = fmaxf(m, __shfl_xor(m, 32));
      if (rg == 0) sred[wid][0][ch] = m;
    }
    __syncthreads();
    {
      int qq = t >> 7, ch = t & 127;
      float v = fmaxf(sred[qq * 2][0][ch], sred[qq * 2 + 1][0][ch]);
      kmaxb[((size_t)blk * 2 + qq) * 128 + ch] = v;
    }
  }
}

// ---------------- transpose kmax (B,S,128) -> out1 (B,128,S)
__global__ __launch_bounds__(256) void k_tr(const float* __restrict__ kmaxb,
                                            float* __restrict__ out1) {
  __shared__ float tile[32][33];
  int t = threadIdx.x, blk = blockIdx.x;
  int b = blk >> 7, rem = blk & 127, ct = rem >> 5, st = rem & 31;
  int c0 = ct * 32, s0 = st * 32;
#pragma unroll
  for (int p = 0; p < 4; ++p)
    tile[(t >> 5) + p * 8][t & 31] =
        kmaxb[(size_t)b * 131072 + (size_t)(s0 + (t >> 5) + p * 8) * 128 + c0 + (t & 31)];
  __syncthreads();
#pragma unroll
  for (int p = 0; p < 4; ++p) {
    int c = c0 + (t >> 5) + p * 8;
    int s = s0 + (t & 31);
    out1[(size_t)b * 131072 + (size_t)c * 1024 + s] = tile[t & 31][(t >> 5) + p * 8];
  }
}

extern "C" void kernel_launch(void* const* d_in, const int* in_sizes, int n_in,
                              void* d_out, int out_size, void* d_ws, size_t ws_size,
                              hipStream_t stream) {
  (void)in_sizes; (void)n_in; (void)out_size;
  const float* xyz    = (const float*)d_in[0];
  const float* points = (const float*)d_in[1];
  const float* w0  = (const float*)d_in[2];
  const float* b0  = (const float*)d_in[3];
  const float* g0  = (const float*)d_in[4];
  const float* be0 = (const float*)d_in[5];
  const float* w1  = (const float*)d_in[6];
  const float* b1  = (const float*)d_in[7];
  const float* g1  = (const float*)d_in[8];
  const float* be1 = (const float*)d_in[9];
  const float* w2  = (const float*)d_in[10];
  const float* b2  = (const float*)d_in[11];
  const float* g2  = (const float*)d_in[12];
  const float* be2 = (const float*)d_in[13];
  float* out  = (float*)d_out;
  float* out0 = out;
  float* out1 = out + 49152;
  float* out2 = out + 49152 + 2097152;
  char* ws = (char*)d_ws;
  const size_t OFF_PT   = 0;         // 16*4096*64*2 = 8388608
  const size_t OFF_XYZ4 = 8388608;   // 1048576
  const size_t OFF_NQ4  = 9437184;   // 262144
  const size_t OFF_FPS  = 9699328;   // 65536
  const size_t OFF_BALL = 9764864;   // 2097152
  const size_t OFF_XBUF = 11862016;  // 67108864
  const size_t OFF_PART = 78970880;  // 8388608
  const size_t OFF_SC   = 87359488;  // 4096
  const size_t OFF_KMAX = 87363584;  // 8388608
  const size_t NEED     = 95752192;
  if (ws_size < NEED) return;
  unsigned short* pT   = (unsigned short*)(ws + OFF_PT);
  float4* xyz4 = (float4*)(ws + OFF_XYZ4);
  float4* nq4  = (float4*)(ws + OFF_NQ4);
  int* fpsidx  = (int*)(ws + OFF_FPS);
  int* ballidx = (int*)(ws + OFF_BALL);
  unsigned short* xbuf = (unsigned short*)(ws + OFF_XBUF);
  float* part  = (float*)(ws + OFF_PART);
  float* scb   = (float*)(ws + OFF_SC);
  float *sc1 = scb, *sh1 = scb + 128, *sc2 = scb + 256, *sh2 = scb + 384,
        *sc3 = scb + 512, *sh3 = scb + 640;
  float* kmaxb = (float*)(ws + OFF_KMAX);

  k_prep<<<1024, 256, 0, stream>>>(points, xyz, pT, xyz4);
  k_fps<<<16, 512, 0, stream>>>(xyz, out0, out2, fpsidx, nq4);
  k_ball<<<1024, 256, 0, stream>>>(xyz4, fpsidx, ballidx);
  k_gemm1<<<8192, 256, 0, stream>>>(pT, xyz4, nq4, ballidx, w0, b0, xbuf, part);
  k_red<<<64, 256, 0, stream>>>(part, 8192, 64, g0, be0, sc1, sh1);
  k_gemm2<<<8192, 256, 0, stream>>>(xbuf, w1, b1, sc1, sh1, part);
  k_red<<<64, 256, 0, stream>>>(part, 8192, 64, g1, be1, sc2, sh2);
  k_gemm3<false><<<8192, 256, 0, stream>>>(xbuf, w2, b2, sc2, sh2, nullptr, nullptr, part, nullptr);
  k_red<<<128, 256, 0, stream>>>(part, 8192, 128, g2, be2, sc3, sh3);
  k_gemm3<true><<<8192, 256, 0, stream>>>(xbuf, w2, b2, sc2, sh2, sc3, sh3, nullptr, kmaxb);
  k_tr<<<2048, 256, 0, stream>>>(kmaxb, out1);
}

// Round 2
// 1223.105 us; speedup vs baseline: 1.6773x; 1.6773x over previous
//
#include <hip/hip_runtime.h>

using f32x4  = __attribute__((ext_vector_type(4))) float;
using short8 = __attribute__((ext_vector_type(8))) short;
using u64x2  = __attribute__((ext_vector_type(2))) unsigned long long;

__device__ __forceinline__ unsigned short f2bf(float f) {
  unsigned u = __builtin_bit_cast(unsigned, f);
  u = (u + 0x7FFFu + ((u >> 16) & 1u)) >> 16;
  return (unsigned short)u;
}
__device__ __forceinline__ float bf2f(unsigned short s) {
  return __builtin_bit_cast(float, ((unsigned)s) << 16);
}
__device__ __forceinline__ double u2d(unsigned long long u) {
  return __builtin_bit_cast(double, u);
}
__device__ __forceinline__ unsigned long long d2u(double d) {
  return __builtin_bit_cast(unsigned long long, d);
}

// ---------------- K0: transpose points (B,64,4096)->bf16 (B,4096,64); xyz -> float4(x,y,z,|p|^2)
__global__ __launch_bounds__(256) void k_prep(const float* __restrict__ points,
                                              const float* __restrict__ xyz,
                                              unsigned short* __restrict__ pT,
                                              float4* __restrict__ xyz4) {
  __shared__ float tile[64][65];
  int t = threadIdx.x, blk = blockIdx.x;
  int b = blk >> 6, n0 = (blk & 63) << 6;
#pragma unroll
  for (int p = 0; p < 16; ++p) {
    int c = p * 4 + (t >> 6);
    tile[c][t & 63] = points[(size_t)b * 262144 + (size_t)c * 4096 + n0 + (t & 63)];
  }
  if (t < 64) {
    int n = n0 + t;
    float x = xyz[(size_t)b * 12288 + n];
    float y = xyz[(size_t)b * 12288 + 4096 + n];
    float z = xyz[(size_t)b * 12288 + 8192 + n];
    float ps = __fadd_rn(__fadd_rn(__fmul_rn(x, x), __fmul_rn(y, y)), __fmul_rn(z, z));
    xyz4[(size_t)b * 4096 + n] = make_float4(x, y, z, ps);
  }
  __syncthreads();
  int nl = t >> 2, coff = (t & 3) * 16;
  unsigned v[8];
#pragma unroll
  for (int j = 0; j < 8; ++j) {
    unsigned lo = f2bf(tile[coff + 2 * j][nl]);
    unsigned hi = f2bf(tile[coff + 2 * j + 1][nl]);
    v[j] = lo | (hi << 16);
  }
  uint4* dst = reinterpret_cast<uint4*>(pT + ((size_t)b * 4096 + n0 + nl) * 64 + coff);
  dst[0] = make_uint4(v[0], v[1], v[2], v[3]);
  dst[1] = make_uint4(v[4], v[5], v[6], v[7]);
}

// ---------------- FPS: 1 block/batch, 4 waves, u64-packed (dist,~idx) argmax via v_max_f64.
// Bitwise-exact f32 distance chain (no FMA contraction); first-index tie-break via ~idx in low bits.
__global__ __launch_bounds__(256) void k_fps(const float* __restrict__ xyz,
                                             float* __restrict__ out0,
                                             float* __restrict__ out2,
                                             int* __restrict__ fpsidx,
                                             float4* __restrict__ nq4) {
  __shared__ float sx[4096], sy[4096], sz[4096];
  __shared__ __align__(16) unsigned long long scand[2][16];
  __shared__ int sfar[1024];
  int b = blockIdx.x, t = threadIdx.x;
  float px[16], py[16], pz[16], dist[16];
  unsigned lo[16];
#pragma unroll
  for (int j = 0; j < 16; ++j) {
    int n = t + (j << 8);
    float x = xyz[(size_t)b * 12288 + n];
    float y = xyz[(size_t)b * 12288 + 4096 + n];
    float z = xyz[(size_t)b * 12288 + 8192 + n];
    px[j] = x; py[j] = y; pz[j] = z; dist[j] = 1e10f;
    lo[j] = ~(unsigned)n;
    sx[n] = x; sy[n] = y; sz[n] = z;
  }
  __syncthreads();
  int lane = t & 63, wid = t >> 6;
  int far = 0;
  float cx = sx[0], cy = sy[0], cz = sz[0];
  for (int it = 0; it < 1024; ++it) {
    sfar[it] = far;   // uniform value, broadcast same-address store
    double best0 = 0.0, best1 = 0.0;
#pragma unroll
    for (int j = 0; j < 16; ++j) {
      float dx = __fsub_rn(px[j], cx);
      float dy = __fsub_rn(py[j], cy);
      float dz = __fsub_rn(pz[j], cz);
      float d  = __fadd_rn(__fadd_rn(__fmul_rn(dx, dx), __fmul_rn(dy, dy)), __fmul_rn(dz, dz));
      float nd = fminf(dist[j], d);
      dist[j] = nd;
      unsigned long long cand =
          ((unsigned long long)__builtin_bit_cast(unsigned, nd) << 32) | lo[j];
      if (j & 1) best1 = fmax(best1, u2d(cand));
      else       best0 = fmax(best0, u2d(cand));
    }
    double best = fmax(best0, best1);
#pragma unroll
    for (int off = 1; off <= 8; off <<= 1) {
      double o = __shfl_xor(best, off);
      best = fmax(best, o);
    }
    int pb = it & 1;
    if ((lane & 15) == 0) scand[pb][(wid << 2) | (lane >> 4)] = d2u(best);
    __syncthreads();
    const u64x2* cp = reinterpret_cast<const u64x2*>(scand[pb]);
    u64x2 q0 = cp[0], q1 = cp[1], q2 = cp[2], q3 = cp[3];
    u64x2 q4 = cp[4], q5 = cp[5], q6 = cp[6], q7 = cp[7];
    double a0 = fmax(u2d(q0[0]), u2d(q0[1]));
    double a1 = fmax(u2d(q1[0]), u2d(q1[1]));
    double a2 = fmax(u2d(q2[0]), u2d(q2[1]));
    double a3 = fmax(u2d(q3[0]), u2d(q3[1]));
    double a4 = fmax(u2d(q4[0]), u2d(q4[1]));
    double a5 = fmax(u2d(q5[0]), u2d(q5[1]));
    double a6 = fmax(u2d(q6[0]), u2d(q6[1]));
    double a7 = fmax(u2d(q7[0]), u2d(q7[1]));
    double b0 = fmax(fmax(a0, a1), fmax(a2, a3));
    double b1 = fmax(fmax(a4, a5), fmax(a6, a7));
    unsigned long long bw = d2u(fmax(b0, b1));
    int n = (int)(~(unsigned)bw) & 4095;
    far = n;
    cx = sx[n]; cy = sy[n]; cz = sz[n];
  }
  __syncthreads();
#pragma unroll
  for (int h = 0; h < 4; ++h) {
    int k = (h << 8) + t;
    int fr = sfar[k];
    float x = sx[fr], y = sy[fr], z = sz[fr];
    fpsidx[(b << 10) + k] = fr;
    out2[(b << 10) + k] = (float)fr;
    out0[(size_t)b * 3072 + k]        = x;
    out0[(size_t)b * 3072 + 1024 + k] = y;
    out0[(size_t)b * 3072 + 2048 + k] = z;
    float ps = __fadd_rn(__fadd_rn(__fmul_rn(x, x), __fmul_rn(y, y)), __fmul_rn(z, z));
    nq4[(b << 10) + k] = make_float4(x, y, z, ps);
  }
}

// ---------------- Ball query: wave/query; compact in-ball; 32x stable (d,idx) extraction
#define BCAP 384
__global__ __launch_bounds__(256) void k_ball(const float4* __restrict__ xyz4,
                                              const int* __restrict__ fpsidx,
                                              int* __restrict__ ballidx) {
  __shared__ float sxs[4096], sys[4096], szs[4096];
  __shared__ float sd[4][BCAP];
  __shared__ int   si[4][BCAP];
  int t = threadIdx.x, blk = blockIdx.x;
  int b = blk >> 6;
  for (int i = t; i < 4096; i += 256) {
    float4 p = xyz4[(size_t)b * 4096 + i];
    sxs[i] = p.x; sys[i] = p.y; szs[i] = p.z;
  }
  __syncthreads();
  int lane = t & 63, wid = t >> 6;
  for (int r = 0; r < 4; ++r) {
    int q = blk * 16 + r * 4 + wid;
    int qi = fpsidx[q];
    float qx = sxs[qi], qy = sys[qi], qz = szs[qi];
    float qs = __fadd_rn(__fadd_rn(__fmul_rn(qx, qx), __fmul_rn(qy, qy)), __fmul_rn(qz, qz));
    int cnt = 0;
    for (int i = 0; i < 64; ++i) {
      int n = (i << 6) + lane;
      float x = sxs[n], y = sys[n], z = szs[n];
      float ps  = __fadd_rn(__fadd_rn(__fmul_rn(x, x), __fmul_rn(y, y)), __fmul_rn(z, z));
      float dot = __fadd_rn(__fadd_rn(__fmul_rn(qx, x), __fmul_rn(qy, y)), __fmul_rn(qz, z));
      float d   = __fadd_rn(__fadd_rn(__fmul_rn(-2.f, dot), qs), ps);   // exact np expansion
      bool in = (d <= 0.04f);   // matches  !(d > f32(0.04))
      unsigned long long m = __ballot(in);
      int pos = cnt + (int)__popcll(m & ((1ull << lane) - 1ull));
      if (in && pos < BCAP) { sd[wid][pos] = d; si[wid][pos] = n; }
      cnt += (int)__popcll(m);
    }
    if (cnt > BCAP) cnt = BCAP;
    float ld[6]; int li[6];
#pragma unroll
    for (int u = 0; u < 6; ++u) {
      int slot = lane + (u << 6);
      bool v = slot < cnt;
      ld[u] = v ? sd[wid][slot] : 1e30f;
      li[u] = v ? si[wid][slot] : 0x7fffffff;
    }
    float pd = -1e30f; int pi = -1; int firstI = 0;
#pragma unroll 1
    for (int rr = 0; rr < 32; ++rr) {
      float bd = 1e30f; int bi = 0x7fffffff;
#pragma unroll
      for (int u = 0; u < 6; ++u) {
        bool gt = (ld[u] > pd) || (ld[u] == pd && li[u] > pi);
        bool lt = (ld[u] < bd) || (ld[u] == bd && li[u] < bi);
        if (gt && lt) { bd = ld[u]; bi = li[u]; }
      }
#pragma unroll
      for (int off = 32; off; off >>= 1) {
        float od = __shfl_xor(bd, off);
        int   oi = __shfl_xor(bi, off);
        if (od < bd || (od == bd && oi < bi)) { bd = od; bi = oi; }
      }
      if (rr == 0) firstI = bi;
      int outv = (bd < 1e30f) ? bi : firstI;   // pad with first (== idx[...,0]) when < 32 in-ball
      if (lane == 0) ballidx[(size_t)q * 32 + rr] = outv;
      if (bd < 1e30f) { pd = bd; pi = bi; }
    }
  }
}

// ---------------- Layer1: gather + bf16 MFMA GEMM (K=96 padded), store x1 bf16 + stats partials
__global__ __launch_bounds__(256) void k_gemm1(const unsigned short* __restrict__ pT,
    const float4* __restrict__ xyz4, const float4* __restrict__ nq4,
    const int* __restrict__ bidx, const float* __restrict__ wgt,
    const float* __restrict__ bia, unsigned short* __restrict__ xbuf,
    float* __restrict__ part) {
  __shared__ unsigned short A[64][104];
  __shared__ unsigned short W[64][104];
  __shared__ float sred[4][2][64];
  int t = threadIdx.x, blk = blockIdx.x;
  int b = blk >> 9;
  for (int e = t; e < 64 * 96; e += 256) {
    int o = e / 96, k = e - o * 96;
    // input channel reorder: A cols [0..63]=points, [64..66]=xyz-norm, rest zero
    float v = (k < 64) ? wgt[o * 67 + 3 + k] : ((k < 67) ? wgt[o * 67 + (k - 64)] : 0.f);
    W[o][k] = f2bf(v);
  }
  {
    int rt = t >> 2, sub = t & 3;
    int q = (blk << 1) + (rt >> 5);
    int n = bidx[(size_t)q * 32 + (rt & 31)];
    const uint4* src = reinterpret_cast<const uint4*>(pT + ((size_t)(b * 4096 + n)) * 64 + sub * 16);
    uint4 v0 = src[0], v1 = src[1];
    *reinterpret_cast<uint4*>(&A[rt][sub * 16])     = v0;
    *reinterpret_cast<uint4*>(&A[rt][sub * 16 + 8]) = v1;
    if (sub == 0) {
      float4 P = xyz4[(size_t)b * 4096 + n];
      float4 Qc = nq4[q];
      A[rt][64] = f2bf(__fsub_rn(P.x, Qc.x));
      A[rt][65] = f2bf(__fsub_rn(P.y, Qc.y));
      A[rt][66] = f2bf(__fsub_rn(P.z, Qc.z));
    } else if (sub == 1) {
#pragma unroll
      for (int k = 67; k < 96; ++k) A[rt][k] = 0;
    }
  }
  __syncthreads();
  int lane = t & 63, wid = t >> 6;
  int cl = lane & 15, rg = lane >> 4;
  int rowb = (wid << 4) + cl, ko = rg << 3;
  f32x4 acc[4] = {};
#pragma unroll
  for (int ks = 0; ks < 96; ks += 32) {
    short8 a = *reinterpret_cast<const short8*>(&A[rowb][ks + ko]);
#pragma unroll
    for (int nt = 0; nt < 4; ++nt) {
      short8 bb = *reinterpret_cast<const short8*>(&W[nt * 16 + cl][ks + ko]);
      acc[nt] = __builtin_amdgcn_mfma_f32_16x16x32_bf16(a, bb, acc[nt], 0, 0, 0);
    }
  }
#pragma unroll
  for (int nt = 0; nt < 4; ++nt) {
    int ch = nt * 16 + cl;
    float bv = bia[ch];
    float v0 = acc[nt][0] + bv, v1 = acc[nt][1] + bv, v2 = acc[nt][2] + bv, v3 = acc[nt][3] + bv;
    size_t gr = (size_t)blk * 64 + (wid << 4) + (rg << 2);
    xbuf[(gr + 0) * 64 + ch] = f2bf(v0);
    xbuf[(gr + 1) * 64 + ch] = f2bf(v1);
    xbuf[(gr + 2) * 64 + ch] = f2bf(v2);
    xbuf[(gr + 3) * 64 + ch] = f2bf(v3);
    float s1 = (v0 + v1) + (v2 + v3);
    float s2 = (v0 * v0 + v1 * v1) + (v2 * v2 + v3 * v3);
    s1 += __shfl_xor(s1, 16); s1 += __shfl_xor(s1, 32);
    s2 += __shfl_xor(s2, 16); s2 += __shfl_xor(s2, 32);
    if (rg == 0) { sred[wid][0][ch] = s1; sred[wid][1][ch] = s2; }
  }
  __syncthreads();
  if (t < 128) {
    int ch = t & 63, wh = t >> 6;
    float v = sred[0][wh][ch] + sred[1][wh][ch] + sred[2][wh][ch] + sred[3][wh][ch];
    part[(size_t)blk * 128 + ch * 2 + wh] = v;
  }
}

// ---------------- stats partial reduce -> folded BN scale/shift
__global__ __launch_bounds__(256) void k_red(const float* __restrict__ part, int nblk, int nch,
    const float* __restrict__ gamma, const float* __restrict__ beta,
    float* __restrict__ scale, float* __restrict__ shift) {
  int c = blockIdx.x, t = threadIdx.x;
  int stride = 2 * nch;
  float s1 = 0.f, s2 = 0.f;
  for (int i = t; i < nblk; i += 256) {
    s1 += part[(size_t)i * stride + 2 * c];
    s2 += part[(size_t)i * stride + 2 * c + 1];
  }
  __shared__ float r1[256], r2[256];
  r1[t] = s1; r2[t] = s2;
  __syncthreads();
  for (int o = 128; o > 0; o >>= 1) {
    if (t < o) { r1[t] += r1[t + o]; r2[t] += r2[t + o]; }
    __syncthreads();
  }
  if (t == 0) {
    const float N = 524288.f;
    float mu = r1[0] / N;
    float var = r2[0] / N - mu * mu;
    float a = gamma[c] / sqrtf(var + 1e-5f);
    scale[c] = a;
    shift[c] = beta[c] - a * mu;
  }
}

// ---------------- Layer2: read x1 (bf16) -> BN1+ReLU -> GEMM -> x2 in-place + stats
__global__ __launch_bounds__(256) void k_gemm2(unsigned short* __restrict__ xbuf,
    const float* __restrict__ wgt, const float* __restrict__ bia,
    const float* __restrict__ sc, const float* __restrict__ sh,
    float* __restrict__ part) {
  __shared__ unsigned short A[64][72];
  __shared__ unsigned short W[64][72];
  __shared__ float ssc[64], ssh[64];
  __shared__ float sred[4][2][64];
  int t = threadIdx.x, blk = blockIdx.x;
  if (t < 64) { ssc[t] = sc[t]; ssh[t] = sh[t]; }
  __syncthreads();
  for (int e = t; e < 4096; e += 256) {
    int o = e >> 6, k = e & 63;
    W[o][k] = f2bf(wgt[(size_t)o * 64 + k]);
  }
  {
    int rt = t >> 2, sub = t & 3;
    size_t gr = (size_t)blk * 64 + rt;
    const uint4* src = reinterpret_cast<const uint4*>(xbuf + gr * 64 + sub * 16);
    uint4 v0 = src[0], v1 = src[1];
    unsigned wv[8] = {v0.x, v0.y, v0.z, v0.w, v1.x, v1.y, v1.z, v1.w};
#pragma unroll
    for (int j = 0; j < 8; ++j) {
      int c = sub * 16 + 2 * j;
      float x0 = bf2f((unsigned short)(wv[j] & 0xffffu));
      float x1 = bf2f((unsigned short)(wv[j] >> 16));
      A[rt][c]     = f2bf(fmaxf(0.f, ssc[c] * x0 + ssh[c]));
      A[rt][c + 1] = f2bf(fmaxf(0.f, ssc[c + 1] * x1 + ssh[c + 1]));
    }
  }
  __syncthreads();
  int lane = t & 63, wid = t >> 6;
  int cl = lane & 15, rg = lane >> 4;
  int rowb = (wid << 4) + cl, ko = rg << 3;
  f32x4 acc[4] = {};
#pragma unroll
  for (int ks = 0; ks < 64; ks += 32) {
    short8 a = *reinterpret_cast<const short8*>(&A[rowb][ks + ko]);
#pragma unroll
    for (int nt = 0; nt < 4; ++nt) {
      short8 bb = *reinterpret_cast<const short8*>(&W[nt * 16 + cl][ks + ko]);
      acc[nt] = __builtin_amdgcn_mfma_f32_16x16x32_bf16(a, bb, acc[nt], 0, 0, 0);
    }
  }
#pragma unroll
  for (int nt = 0; nt < 4; ++nt) {
    int ch = nt * 16 + cl;
    float bv = bia[ch];
    float v0 = acc[nt][0] + bv, v1 = acc[nt][1] + bv, v2 = acc[nt][2] + bv, v3 = acc[nt][3] + bv;
    size_t gr = (size_t)blk * 64 + (wid << 4) + (rg << 2);
    xbuf[(gr + 0) * 64 + ch] = f2bf(v0);
    xbuf[(gr + 1) * 64 + ch] = f2bf(v1);
    xbuf[(gr + 2) * 64 + ch] = f2bf(v2);
    xbuf[(gr + 3) * 64 + ch] = f2bf(v3);
    float s1 = (v0 + v1) + (v2 + v3);
    float s2 = (v0 * v0 + v1 * v1) + (v2 * v2 + v3 * v3);
    s1 += __shfl_xor(s1, 16); s1 += __shfl_xor(s1, 32);
    s2 += __shfl_xor(s2, 16); s2 += __shfl_xor(s2, 32);
    if (rg == 0) { sred[wid][0][ch] = s1; sred[wid][1][ch] = s2; }
  }
  __syncthreads();
  if (t < 128) {
    int ch = t & 63, wh = t >> 6;
    float v = sred[0][wh][ch] + sred[1][wh][ch] + sred[2][wh][ch] + sred[3][wh][ch];
    part[(size_t)blk * 128 + ch * 2 + wh] = v;
  }
}

// ---------------- Layer3 (N=128): STATS pass, then FINAL pass (recompute + BN3+ReLU + k-max)
template<bool FINAL>
__global__ __launch_bounds__(256) void k_gemm3(const unsigned short* __restrict__ xbuf,
    const float* __restrict__ wgt, const float* __restrict__ bia,
    const float* __restrict__ sc2, const float* __restrict__ sh2,
    const float* __restrict__ sc3, const float* __restrict__ sh3,
    float* __restrict__ part, float* __restrict__ kmaxb) {
  __shared__ unsigned short A[64][72];
  __shared__ unsigned short W[128][72];
  __shared__ float ssc[64], ssh[64];
  __shared__ float s3c[128], s3h[128];
  __shared__ float sred[4][2][128];
  int t = threadIdx.x, blk = blockIdx.x;
  if (t < 64) { ssc[t] = sc2[t]; ssh[t] = sh2[t]; }
  if (FINAL && t >= 128) { s3c[t - 128] = sc3[t - 128]; s3h[t - 128] = sh3[t - 128]; }
  __syncthreads();
  for (int e = t; e < 8192; e += 256) {
    int o = e >> 6, k = e & 63;
    W[o][k] = f2bf(wgt[(size_t)o * 64 + k]);
  }
  {
    int rt = t >> 2, sub = t & 3;
    size_t gr = (size_t)blk * 64 + rt;
    const uint4* src = reinterpret_cast<const uint4*>(xbuf + gr * 64 + sub * 16);
    uint4 v0 = src[0], v1 = src[1];
    unsigned wv[8] = {v0.x, v0.y, v0.z, v0.w, v1.x, v1.y, v1.z, v1.w};
#pragma unroll
    for (int j = 0; j < 8; ++j) {
      int c = sub * 16 + 2 * j;
      float x0 = bf2f((unsigned short)(wv[j] & 0xffffu));
      float x1 = bf2f((unsigned short)(wv[j] >> 16));
      A[rt][c]     = f2bf(fmaxf(0.f, ssc[c] * x0 + ssh[c]));
      A[rt][c + 1] = f2bf(fmaxf(0.f, ssc[c + 1] * x1 + ssh[c + 1]));
    }
  }
  __syncthreads();
  int lane = t & 63, wid = t >> 6;
  int cl = lane & 15, rg = lane >> 4;
  int rowb = (wid << 4) + cl, ko = rg << 3;
  f32x4 acc[8] = {};
#pragma unroll
  for (int ks = 0; ks < 64; ks += 32) {
    short8 a = *reinterpret_cast<const short8*>(&A[rowb][ks + ko]);
#pragma unroll
    for (int nt = 0; nt < 8; ++nt) {
      short8 bb = *reinterpret_cast<const short8*>(&W[nt * 16 + cl][ks + ko]);
      acc[nt] = __builtin_amdgcn_mfma_f32_16x16x32_bf16(a, bb, acc[nt], 0, 0, 0);
    }
  }
  if (!FINAL) {
#pragma unroll
    for (int nt = 0; nt < 8; ++nt) {
      int ch = nt * 16 + cl;
      float bv = bia[ch];
      float v0 = acc[nt][0] + bv, v1 = acc[nt][1] + bv, v2 = acc[nt][2] + bv, v3 = acc[nt][3] + bv;
      float s1 = (v0 + v1) + (v2 + v3);
      float s2 = (v0 * v0 + v1 * v1) + (v2 * v2 + v3 * v3);
      s1 += __shfl_xor(s1, 16); s1 += __shfl_xor(s1, 32);
      s2 += __shfl_xor(s2, 16); s2 += __shfl_xor(s2, 32);
      if (rg == 0) { sred[wid][0][ch] = s1; sred[wid][1][ch] = s2; }
    }
    __syncthreads();
    {
      int ch = t & 127, wh = t >> 7;
      float v = sred[0][wh][ch] + sred[1][wh][ch] + sred[2][wh][ch] + sred[3][wh][ch];
      part[(size_t)blk * 256 + ch * 2 + wh] = v;
    }
  } else {
#pragma unroll
    for (int nt = 0; nt < 8; ++nt) {
      int ch = nt * 16 + cl;
      float bv = bia[ch];
      float a0 = fmaxf(0.f, s3c[ch] * (acc[nt][0] + bv) + s3h[ch]);
      float a1 = fmaxf(0.f, s3c[ch] * (acc[nt][1] + bv) + s3h[ch]);
      float a2 = fmaxf(0.f, s3c[ch] * (acc[nt][2] + bv) + s3h[ch]);
      float a3 = fmaxf(0.f, s3c[ch] * (acc[nt][3] + bv) + s3h[ch]);
      float m = fmaxf(fmaxf(a0, a1), fmaxf(a2, a3));
      m = fmaxf(m, __shfl_xor(m, 16));
      m = fmaxf(m, __shfl_xor(m, 32));
      if (rg == 0) sred[wid][0][ch] = m;
    }
    __syncthreads();
    {
      int qq = t >> 7, ch = t & 127;
      float v = fmaxf(sred[qq * 2][0][ch], sred[qq * 2 + 1][0][ch]);
      kmaxb[((size_t)blk * 2 + qq) * 128 + ch] = v;
    }
  }
}

// ---------------- transpose kmax (B,S,128) -> out1 (B,128,S)
__global__ __launch_bounds__(256) void k_tr(const float* __restrict__ kmaxb,
                                            float* __restrict__ out1) {
  __shared__ float tile[32][33];
  int t = threadIdx.x, blk = blockIdx.x;
  int b = blk >> 7, rem = blk & 127, ct = rem >> 5, st = rem & 31;
  int c0 = ct * 32, s0 = st * 32;
#pragma unroll
  for (int p = 0; p < 4; ++p)
    tile[(t >> 5) + p * 8][t & 31] =
        kmaxb[(size_t)b * 131072 + (size_t)(s0 + (t >> 5) + p * 8) * 128 + c0 + (t & 31)];
  __syncthreads();
#pragma unroll
  for (int p = 0; p < 4; ++p) {
    int c = c0 + (t >> 5) + p * 8;
    int s = s0 + (t & 31);
    out1[(size_t)b * 131072 + (size_t)c * 1024 + s] = tile[t & 31][(t >> 5) + p * 8];
  }
}

extern "C" void kernel_launch(void* const* d_in, const int* in_sizes, int n_in,
                              void* d_out, int out_size, void* d_ws, size_t ws_size,
                              hipStream_t stream) {
  (void)in_sizes; (void)n_in; (void)out_size;
  const float* xyz    = (const float*)d_in[0];
  const float* points = (const float*)d_in[1];
  const float* w0  = (const float*)d_in[2];
  const float* b0  = (const float*)d_in[3];
  const float* g0  = (const float*)d_in[4];
  const float* be0 = (const float*)d_in[5];
  const float* w1  = (const float*)d_in[6];
  const float* b1  = (const float*)d_in[7];
  const float* g1  = (const float*)d_in[8];
  const float* be1 = (const float*)d_in[9];
  const float* w2  = (const float*)d_in[10];
  const float* b2  = (const float*)d_in[11];
  const float* g2  = (const float*)d_in[12];
  const float* be2 = (const float*)d_in[13];
  float* out  = (float*)d_out;
  float* out0 = out;
  float* out1 = out + 49152;
  float* out2 = out + 49152 + 2097152;
  char* ws = (char*)d_ws;
  const size_t OFF_PT   = 0;         // 16*4096*64*2 = 8388608
  const size_t OFF_XYZ4 = 8388608;   // 1048576
  const size_t OFF_NQ4  = 9437184;   // 262144
  const size_t OFF_FPS  = 9699328;   // 65536
  const size_t OFF_BALL = 9764864;   // 2097152
  const size_t OFF_XBUF = 11862016;  // 67108864
  const size_t OFF_PART = 78970880;  // 8388608
  const size_t OFF_SC   = 87359488;  // 4096
  const size_t OFF_KMAX = 87363584;  // 8388608
  const size_t NEED     = 95752192;
  if (ws_size < NEED) return;
  unsigned short* pT   = (unsigned short*)(ws + OFF_PT);
  float4* xyz4 = (float4*)(ws + OFF_XYZ4);
  float4* nq4  = (float4*)(ws + OFF_NQ4);
  int* fpsidx  = (int*)(ws + OFF_FPS);
  int* ballidx = (int*)(ws + OFF_BALL);
  unsigned short* xbuf = (unsigned short*)(ws + OFF_XBUF);
  float* part  = (float*)(ws + OFF_PART);
  float* scb   = (float*)(ws + OFF_SC);
  float *sc1 = scb, *sh1 = scb + 128, *sc2 = scb + 256, *sh2 = scb + 384,
        *sc3 = scb + 512, *sh3 = scb + 640;
  float* kmaxb = (float*)(ws + OFF_KMAX);

  k_prep<<<1024, 256, 0, stream>>>(points, xyz, pT, xyz4);
  k_fps<<<16, 256, 0, stream>>>(xyz, out0, out2, fpsidx, nq4);
  k_ball<<<1024, 256, 0, stream>>>(xyz4, fpsidx, ballidx);
  k_gemm1<<<8192, 256, 0, stream>>>(pT, xyz4, nq4, ballidx, w0, b0, xbuf, part);
  k_red<<<64, 256, 0, stream>>>(part, 8192, 64, g0, be0, sc1, sh1);
  k_gemm2<<<8192, 256, 0, stream>>>(xbuf, w1, b1, sc1, sh1, part);
  k_red<<<64, 256, 0, stream>>>(part, 8192, 64, g1, be1, sc2, sh2);
  k_gemm3<false><<<8192, 256, 0, stream>>>(xbuf, w2, b2, sc2, sh2, nullptr, nullptr, part, nullptr);
  k_red<<<128, 256, 0, stream>>>(part, 8192, 128, g2, be2, sc3, sh3);
  k_gemm3<true><<<8192, 256, 0, stream>>>(xbuf, w2, b2, sc2, sh2, sc3, sh3, nullptr, kmaxb);
  k_tr<<<2048, 256, 0, stream>>>(kmaxb, out1);
}

// Round 3
// 1151.541 us; speedup vs baseline: 1.7815x; 1.0621x over previous
//
#include <hip/hip_runtime.h>

using f32x4  = __attribute__((ext_vector_type(4))) float;
using short8 = __attribute__((ext_vector_type(8))) short;
using u64x2  = __attribute__((ext_vector_type(2))) unsigned long long;

__device__ __forceinline__ unsigned short f2bf(float f) {
  unsigned u = __builtin_bit_cast(unsigned, f);
  u = (u + 0x7FFFu + ((u >> 16) & 1u)) >> 16;
  return (unsigned short)u;
}
__device__ __forceinline__ float bf2f(unsigned short s) {
  return __builtin_bit_cast(float, ((unsigned)s) << 16);
}
__device__ __forceinline__ double u2d(unsigned long long u) {
  return __builtin_bit_cast(double, u);
}
__device__ __forceinline__ unsigned long long d2u(double d) {
  return __builtin_bit_cast(unsigned long long, d);
}

// DPP-based partner fetch + f64 max (reduction within 16-lane rows; no DS pipe).
template <int CTRL>
__device__ __forceinline__ double dpp_max_f64(double best) {
  unsigned long long u = d2u(best);
  int lo32 = (int)(unsigned)u;
  int hi32 = (int)(unsigned)(u >> 32);
  int plo = __builtin_amdgcn_update_dpp(0, lo32, CTRL, 0xF, 0xF, true);
  int phi = __builtin_amdgcn_update_dpp(0, hi32, CTRL, 0xF, 0xF, true);
  unsigned long long p =
      ((unsigned long long)(unsigned)phi << 32) | (unsigned long long)(unsigned)plo;
  return fmax(best, u2d(p));
}

// ---------------- K0: transpose points (B,64,4096)->bf16 (B,4096,64); xyz -> float4(x,y,z,|p|^2)
__global__ __launch_bounds__(256) void k_prep(const float* __restrict__ points,
                                              const float* __restrict__ xyz,
                                              unsigned short* __restrict__ pT,
                                              float4* __restrict__ xyz4) {
  __shared__ float tile[64][65];
  int t = threadIdx.x, blk = blockIdx.x;
  int b = blk >> 6, n0 = (blk & 63) << 6;
#pragma unroll
  for (int p = 0; p < 16; ++p) {
    int c = p * 4 + (t >> 6);
    tile[c][t & 63] = points[(size_t)b * 262144 + (size_t)c * 4096 + n0 + (t & 63)];
  }
  if (t < 64) {
    int n = n0 + t;
    float x = xyz[(size_t)b * 12288 + n];
    float y = xyz[(size_t)b * 12288 + 4096 + n];
    float z = xyz[(size_t)b * 12288 + 8192 + n];
    float ps = __fadd_rn(__fadd_rn(__fmul_rn(x, x), __fmul_rn(y, y)), __fmul_rn(z, z));
    xyz4[(size_t)b * 4096 + n] = make_float4(x, y, z, ps);
  }
  __syncthreads();
  int nl = t >> 2, coff = (t & 3) * 16;
  unsigned v[8];
#pragma unroll
  for (int j = 0; j < 8; ++j) {
    unsigned lo = f2bf(tile[coff + 2 * j][nl]);
    unsigned hi = f2bf(tile[coff + 2 * j + 1][nl]);
    v[j] = lo | (hi << 16);
  }
  uint4* dst = reinterpret_cast<uint4*>(pT + ((size_t)b * 4096 + n0 + nl) * 64 + coff);
  dst[0] = make_uint4(v[0], v[1], v[2], v[3]);
  dst[1] = make_uint4(v[4], v[5], v[6], v[7]);
}

// ---------------- FPS: 1 block/batch, 4 waves, u64-packed (dist,~idx) argmax via v_max_f64.
// px/py/pz/dist pinned in VGPRs; cross-lane reduce via DPP (quad_perm + row_ror).
__global__ __launch_bounds__(256, 1) void k_fps(const float* __restrict__ xyz,
                                                float* __restrict__ out0,
                                                float* __restrict__ out2,
                                                int* __restrict__ fpsidx,
                                                float4* __restrict__ nq4) {
  __shared__ __align__(16) float4 sp4[4096];
  __shared__ __align__(16) unsigned long long scand[2][16];
  __shared__ int sfar[1024];
  int b = blockIdx.x, t = threadIdx.x;
  float px[16], py[16], pz[16], dist[16];
#pragma unroll
  for (int j = 0; j < 16; ++j) {
    int n = t + (j << 8);
    float x = xyz[(size_t)b * 12288 + n];
    float y = xyz[(size_t)b * 12288 + 4096 + n];
    float z = xyz[(size_t)b * 12288 + 8192 + n];
    px[j] = x; py[j] = y; pz[j] = z; dist[j] = 1e10f;
    sp4[n] = make_float4(x, y, z, 0.f);
  }
  __syncthreads();
#pragma unroll
  for (int j = 0; j < 16; ++j) {
    asm volatile("" : "+v"(px[j]), "+v"(py[j]), "+v"(pz[j]));
  }
  unsigned nt = ~(unsigned)t;
  int far = 0;
  float cx = sp4[0].x, cy = sp4[0].y, cz = sp4[0].z;
  for (int it = 0; it < 1024; ++it) {
    if (t == 0) sfar[it] = far;
    double best0 = 0.0, best1 = 0.0;
#pragma unroll
    for (int j = 0; j < 16; ++j) {
      float dx = __fsub_rn(px[j], cx);
      float dy = __fsub_rn(py[j], cy);
      float dz = __fsub_rn(pz[j], cz);
      float d  = __fadd_rn(__fadd_rn(__fmul_rn(dx, dx), __fmul_rn(dy, dy)), __fmul_rn(dz, dz));
      float nd = fminf(dist[j], d);
      dist[j] = nd;
      unsigned long long cand =
          ((unsigned long long)__builtin_bit_cast(unsigned, nd) << 32) |
          (unsigned long long)(nt - (unsigned)(j << 8));   // ~(t + j*256)
      if (j & 1) best1 = fmax(best1, u2d(cand));
      else       best0 = fmax(best0, u2d(cand));
    }
    double best = fmax(best0, best1);
    best = dpp_max_f64<0xB1>(best);   // quad_perm(1,0,3,2)  = xor1
    best = dpp_max_f64<0x4E>(best);   // quad_perm(2,3,0,1)  = xor2
    best = dpp_max_f64<0x124>(best);  // row_ror:4
    best = dpp_max_f64<0x128>(best);  // row_ror:8 -> all 16 lanes of each row hold row max
    int pb = it & 1;
    if ((t & 15) == 0) scand[pb][t >> 4] = d2u(best);
    __syncthreads();
    const u64x2* cp = reinterpret_cast<const u64x2*>(scand[pb]);
    u64x2 q0 = cp[0], q1 = cp[1], q2 = cp[2], q3 = cp[3];
    u64x2 q4 = cp[4], q5 = cp[5], q6 = cp[6], q7 = cp[7];
    double a0 = fmax(u2d(q0[0]), u2d(q0[1]));
    double a1 = fmax(u2d(q1[0]), u2d(q1[1]));
    double a2 = fmax(u2d(q2[0]), u2d(q2[1]));
    double a3 = fmax(u2d(q3[0]), u2d(q3[1]));
    double a4 = fmax(u2d(q4[0]), u2d(q4[1]));
    double a5 = fmax(u2d(q5[0]), u2d(q5[1]));
    double a6 = fmax(u2d(q6[0]), u2d(q6[1]));
    double a7 = fmax(u2d(q7[0]), u2d(q7[1]));
    double b0 = fmax(fmax(a0, a1), fmax(a2, a3));
    double b1 = fmax(fmax(a4, a5), fmax(a6, a7));
    unsigned long long bw = d2u(fmax(b0, b1));
    int n = (int)(~(unsigned)bw) & 4095;
    far = n;
    float4 c4 = sp4[n];
    cx = c4.x; cy = c4.y; cz = c4.z;
  }
  __syncthreads();
#pragma unroll
  for (int h = 0; h < 4; ++h) {
    int k = (h << 8) + t;
    int fr = sfar[k];
    float4 p = sp4[fr];
    float x = p.x, y = p.y, z = p.z;
    fpsidx[(b << 10) + k] = fr;
    out2[(b << 10) + k] = (float)fr;
    out0[(size_t)b * 3072 + k]        = x;
    out0[(size_t)b * 3072 + 1024 + k] = y;
    out0[(size_t)b * 3072 + 2048 + k] = z;
    float ps = __fadd_rn(__fadd_rn(__fmul_rn(x, x), __fmul_rn(y, y)), __fmul_rn(z, z));
    nq4[(b << 10) + k] = make_float4(x, y, z, ps);
  }
}

// ---------------- Ball query: wave/query; compact in-ball; 32x stable (d,idx) extraction
#define BCAP 384
__global__ __launch_bounds__(256) void k_ball(const float4* __restrict__ xyz4,
                                              const int* __restrict__ fpsidx,
                                              int* __restrict__ ballidx) {
  __shared__ float sxs[4096], sys[4096], szs[4096];
  __shared__ float sd[4][BCAP];
  __shared__ int   si[4][BCAP];
  int t = threadIdx.x, blk = blockIdx.x;
  int b = blk >> 6;
  for (int i = t; i < 4096; i += 256) {
    float4 p = xyz4[(size_t)b * 4096 + i];
    sxs[i] = p.x; sys[i] = p.y; szs[i] = p.z;
  }
  __syncthreads();
  int lane = t & 63, wid = t >> 6;
  for (int r = 0; r < 4; ++r) {
    int q = blk * 16 + r * 4 + wid;
    int qi = fpsidx[q];
    float qx = sxs[qi], qy = sys[qi], qz = szs[qi];
    float qs = __fadd_rn(__fadd_rn(__fmul_rn(qx, qx), __fmul_rn(qy, qy)), __fmul_rn(qz, qz));
    int cnt = 0;
    for (int i = 0; i < 64; ++i) {
      int n = (i << 6) + lane;
      float x = sxs[n], y = sys[n], z = szs[n];
      float ps  = __fadd_rn(__fadd_rn(__fmul_rn(x, x), __fmul_rn(y, y)), __fmul_rn(z, z));
      float dot = __fadd_rn(__fadd_rn(__fmul_rn(qx, x), __fmul_rn(qy, y)), __fmul_rn(qz, z));
      float d   = __fadd_rn(__fadd_rn(__fmul_rn(-2.f, dot), qs), ps);   // exact np expansion
      bool in = (d <= 0.04f);   // matches  !(d > f32(0.04))
      unsigned long long m = __ballot(in);
      int pos = cnt + (int)__popcll(m & ((1ull << lane) - 1ull));
      if (in && pos < BCAP) { sd[wid][pos] = d; si[wid][pos] = n; }
      cnt += (int)__popcll(m);
    }
    if (cnt > BCAP) cnt = BCAP;
    float ld[6]; int li[6];
#pragma unroll
    for (int u = 0; u < 6; ++u) {
      int slot = lane + (u << 6);
      bool v = slot < cnt;
      ld[u] = v ? sd[wid][slot] : 1e30f;
      li[u] = v ? si[wid][slot] : 0x7fffffff;
    }
    float pd = -1e30f; int pi = -1; int firstI = 0;
#pragma unroll 1
    for (int rr = 0; rr < 32; ++rr) {
      float bd = 1e30f; int bi = 0x7fffffff;
#pragma unroll
      for (int u = 0; u < 6; ++u) {
        bool gt = (ld[u] > pd) || (ld[u] == pd && li[u] > pi);
        bool lt = (ld[u] < bd) || (ld[u] == bd && li[u] < bi);
        if (gt && lt) { bd = ld[u]; bi = li[u]; }
      }
#pragma unroll
      for (int off = 32; off; off >>= 1) {
        float od = __shfl_xor(bd, off);
        int   oi = __shfl_xor(bi, off);
        if (od < bd || (od == bd && oi < bi)) { bd = od; bi = oi; }
      }
      if (rr == 0) firstI = bi;
      int outv = (bd < 1e30f) ? bi : firstI;   // pad with first (== idx[...,0]) when < 32 in-ball
      if (lane == 0) ballidx[(size_t)q * 32 + rr] = outv;
      if (bd < 1e30f) { pd = bd; pi = bi; }
    }
  }
}

// ---------------- Layer1: gather + bf16 MFMA GEMM (K=96 padded), store x1 bf16 + stats partials
__global__ __launch_bounds__(256) void k_gemm1(const unsigned short* __restrict__ pT,
    const float4* __restrict__ xyz4, const float4* __restrict__ nq4,
    const int* __restrict__ bidx, const float* __restrict__ wgt,
    const float* __restrict__ bia, unsigned short* __restrict__ xbuf,
    float* __restrict__ part) {
  __shared__ unsigned short A[64][104];
  __shared__ unsigned short W[64][104];
  __shared__ float sred[4][2][64];
  int t = threadIdx.x, blk = blockIdx.x;
  int b = blk >> 9;
  for (int e = t; e < 64 * 96; e += 256) {
    int o = e / 96, k = e - o * 96;
    // input channel reorder: A cols [0..63]=points, [64..66]=xyz-norm, rest zero
    float v = (k < 64) ? wgt[o * 67 + 3 + k] : ((k < 67) ? wgt[o * 67 + (k - 64)] : 0.f);
    W[o][k] = f2bf(v);
  }
  {
    int rt = t >> 2, sub = t & 3;
    int q = (blk << 1) + (rt >> 5);
    int n = bidx[(size_t)q * 32 + (rt & 31)];
    const uint4* src = reinterpret_cast<const uint4*>(pT + ((size_t)(b * 4096 + n)) * 64 + sub * 16);
    uint4 v0 = src[0], v1 = src[1];
    *reinterpret_cast<uint4*>(&A[rt][sub * 16])     = v0;
    *reinterpret_cast<uint4*>(&A[rt][sub * 16 + 8]) = v1;
    if (sub == 0) {
      float4 P = xyz4[(size_t)b * 4096 + n];
      float4 Qc = nq4[q];
      A[rt][64] = f2bf(__fsub_rn(P.x, Qc.x));
      A[rt][65] = f2bf(__fsub_rn(P.y, Qc.y));
      A[rt][66] = f2bf(__fsub_rn(P.z, Qc.z));
    } else if (sub == 1) {
#pragma unroll
      for (int k = 67; k < 96; ++k) A[rt][k] = 0;
    }
  }
  __syncthreads();
  int lane = t & 63, wid = t >> 6;
  int cl = lane & 15, rg = lane >> 4;
  int rowb = (wid << 4) + cl, ko = rg << 3;
  f32x4 acc[4] = {};
#pragma unroll
  for (int ks = 0; ks < 96; ks += 32) {
    short8 a = *reinterpret_cast<const short8*>(&A[rowb][ks + ko]);
#pragma unroll
    for (int nt = 0; nt < 4; ++nt) {
      short8 bb = *reinterpret_cast<const short8*>(&W[nt * 16 + cl][ks + ko]);
      acc[nt] = __builtin_amdgcn_mfma_f32_16x16x32_bf16(a, bb, acc[nt], 0, 0, 0);
    }
  }
#pragma unroll
  for (int nt = 0; nt < 4; ++nt) {
    int ch = nt * 16 + cl;
    float bv = bia[ch];
    float v0 = acc[nt][0] + bv, v1 = acc[nt][1] + bv, v2 = acc[nt][2] + bv, v3 = acc[nt][3] + bv;
    size_t gr = (size_t)blk * 64 + (wid << 4) + (rg << 2);
    xbuf[(gr + 0) * 64 + ch] = f2bf(v0);
    xbuf[(gr + 1) * 64 + ch] = f2bf(v1);
    xbuf[(gr + 2) * 64 + ch] = f2bf(v2);
    xbuf[(gr + 3) * 64 + ch] = f2bf(v3);
    float s1 = (v0 + v1) + (v2 + v3);
    float s2 = (v0 * v0 + v1 * v1) + (v2 * v2 + v3 * v3);
    s1 += __shfl_xor(s1, 16); s1 += __shfl_xor(s1, 32);
    s2 += __shfl_xor(s2, 16); s2 += __shfl_xor(s2, 32);
    if (rg == 0) { sred[wid][0][ch] = s1; sred[wid][1][ch] = s2; }
  }
  __syncthreads();
  if (t < 128) {
    int ch = t & 63, wh = t >> 6;
    float v = sred[0][wh][ch] + sred[1][wh][ch] + sred[2][wh][ch] + sred[3][wh][ch];
    part[(size_t)blk * 128 + ch * 2 + wh] = v;
  }
}

// ---------------- stats partial reduce -> folded BN scale/shift
__global__ __launch_bounds__(256) void k_red(const float* __restrict__ part, int nblk, int nch,
    const float* __restrict__ gamma, const float* __restrict__ beta,
    float* __restrict__ scale, float* __restrict__ shift) {
  int c = blockIdx.x, t = threadIdx.x;
  int stride = 2 * nch;
  float s1 = 0.f, s2 = 0.f;
  for (int i = t; i < nblk; i += 256) {
    s1 += part[(size_t)i * stride + 2 * c];
    s2 += part[(size_t)i * stride + 2 * c + 1];
  }
  __shared__ float r1[256], r2[256];
  r1[t] = s1; r2[t] = s2;
  __syncthreads();
  for (int o = 128; o > 0; o >>= 1) {
    if (t < o) { r1[t] += r1[t + o]; r2[t] += r2[t + o]; }
    __syncthreads();
  }
  if (t == 0) {
    const float N = 524288.f;
    float mu = r1[0] / N;
    float var = r2[0] / N - mu * mu;
    float a = gamma[c] / sqrtf(var + 1e-5f);
    scale[c] = a;
    shift[c] = beta[c] - a * mu;
  }
}

// ---------------- Layer2: read x1 (bf16) -> BN1+ReLU -> GEMM -> x2 in-place + stats
__global__ __launch_bounds__(256) void k_gemm2(unsigned short* __restrict__ xbuf,
    const float* __restrict__ wgt, const float* __restrict__ bia,
    const float* __restrict__ sc, const float* __restrict__ sh,
    float* __restrict__ part) {
  __shared__ unsigned short A[64][72];
  __shared__ unsigned short W[64][72];
  __shared__ float ssc[64], ssh[64];
  __shared__ float sred[4][2][64];
  int t = threadIdx.x, blk = blockIdx.x;
  if (t < 64) { ssc[t] = sc[t]; ssh[t] = sh[t]; }
  __syncthreads();
  for (int e = t; e < 4096; e += 256) {
    int o = e >> 6, k = e & 63;
    W[o][k] = f2bf(wgt[(size_t)o * 64 + k]);
  }
  {
    int rt = t >> 2, sub = t & 3;
    size_t gr = (size_t)blk * 64 + rt;
    const uint4* src = reinterpret_cast<const uint4*>(xbuf + gr * 64 + sub * 16);
    uint4 v0 = src[0], v1 = src[1];
    unsigned wv[8] = {v0.x, v0.y, v0.z, v0.w, v1.x, v1.y, v1.z, v1.w};
#pragma unroll
    for (int j = 0; j < 8; ++j) {
      int c = sub * 16 + 2 * j;
      float x0 = bf2f((unsigned short)(wv[j] & 0xffffu));
      float x1 = bf2f((unsigned short)(wv[j] >> 16));
      A[rt][c]     = f2bf(fmaxf(0.f, ssc[c] * x0 + ssh[c]));
      A[rt][c + 1] = f2bf(fmaxf(0.f, ssc[c + 1] * x1 + ssh[c + 1]));
    }
  }
  __syncthreads();
  int lane = t & 63, wid = t >> 6;
  int cl = lane & 15, rg = lane >> 4;
  int rowb = (wid << 4) + cl, ko = rg << 3;
  f32x4 acc[4] = {};
#pragma unroll
  for (int ks = 0; ks < 64; ks += 32) {
    short8 a = *reinterpret_cast<const short8*>(&A[rowb][ks + ko]);
#pragma unroll
    for (int nt = 0; nt < 4; ++nt) {
      short8 bb = *reinterpret_cast<const short8*>(&W[nt * 16 + cl][ks + ko]);
      acc[nt] = __builtin_amdgcn_mfma_f32_16x16x32_bf16(a, bb, acc[nt], 0, 0, 0);
    }
  }
#pragma unroll
  for (int nt = 0; nt < 4; ++nt) {
    int ch = nt * 16 + cl;
    float bv = bia[ch];
    float v0 = acc[nt][0] + bv, v1 = acc[nt][1] + bv, v2 = acc[nt][2] + bv, v3 = acc[nt][3] + bv;
    size_t gr = (size_t)blk * 64 + (wid << 4) + (rg << 2);
    xbuf[(gr + 0) * 64 + ch] = f2bf(v0);
    xbuf[(gr + 1) * 64 + ch] = f2bf(v1);
    xbuf[(gr + 2) * 64 + ch] = f2bf(v2);
    xbuf[(gr + 3) * 64 + ch] = f2bf(v3);
    float s1 = (v0 + v1) + (v2 + v3);
    float s2 = (v0 * v0 + v1 * v1) + (v2 * v2 + v3 * v3);
    s1 += __shfl_xor(s1, 16); s1 += __shfl_xor(s1, 32);
    s2 += __shfl_xor(s2, 16); s2 += __shfl_xor(s2, 32);
    if (rg == 0) { sred[wid][0][ch] = s1; sred[wid][1][ch] = s2; }
  }
  __syncthreads();
  if (t < 128) {
    int ch = t & 63, wh = t >> 6;
    float v = sred[0][wh][ch] + sred[1][wh][ch] + sred[2][wh][ch] + sred[3][wh][ch];
    part[(size_t)blk * 128 + ch * 2 + wh] = v;
  }
}

// ---------------- Layer3 (N=128): STATS pass, then FINAL pass (recompute + BN3+ReLU + k-max)
template<bool FINAL>
__global__ __launch_bounds__(256) void k_gemm3(const unsigned short* __restrict__ xbuf,
    const float* __restrict__ wgt, const float* __restrict__ bia,
    const float* __restrict__ sc2, const float* __restrict__ sh2,
    const float* __restrict__ sc3, const float* __restrict__ sh3,
    float* __restrict__ part, float* __restrict__ kmaxb) {
  __shared__ unsigned short A[64][72];
  __shared__ unsigned short W[128][72];
  __shared__ float ssc[64], ssh[64];
  __shared__ float s3c[128], s3h[128];
  __shared__ float sred[4][2][128];
  int t = threadIdx.x, blk = blockIdx.x;
  if (t < 64) { ssc[t] = sc2[t]; ssh[t] = sh2[t]; }
  if (FINAL && t >= 128) { s3c[t - 128] = sc3[t - 128]; s3h[t - 128] = sh3[t - 128]; }
  __syncthreads();
  for (int e = t; e < 8192; e += 256) {
    int o = e >> 6, k = e & 63;
    W[o][k] = f2bf(wgt[(size_t)o * 64 + k]);
  }
  {
    int rt = t >> 2, sub = t & 3;
    size_t gr = (size_t)blk * 64 + rt;
    const uint4* src = reinterpret_cast<const uint4*>(xbuf + gr * 64 + sub * 16);
    uint4 v0 = src[0], v1 = src[1];
    unsigned wv[8] = {v0.x, v0.y, v0.z, v0.w, v1.x, v1.y, v1.z, v1.w};
#pragma unroll
    for (int j = 0; j < 8; ++j) {
      int c = sub * 16 + 2 * j;
      float x0 = bf2f((unsigned short)(wv[j] & 0xffffu));
      float x1 = bf2f((unsigned short)(wv[j] >> 16));
      A[rt][c]     = f2bf(fmaxf(0.f, ssc[c] * x0 + ssh[c]));
      A[rt][c + 1] = f2bf(fmaxf(0.f, ssc[c + 1] * x1 + ssh[c + 1]));
    }
  }
  __syncthreads();
  int lane = t & 63, wid = t >> 6;
  int cl = lane & 15, rg = lane >> 4;
  int rowb = (wid << 4) + cl, ko = rg << 3;
  f32x4 acc[8] = {};
#pragma unroll
  for (int ks = 0; ks < 64; ks += 32) {
    short8 a = *reinterpret_cast<const short8*>(&A[rowb][ks + ko]);
#pragma unroll
    for (int nt = 0; nt < 8; ++nt) {
      short8 bb = *reinterpret_cast<const short8*>(&W[nt * 16 + cl][ks + ko]);
      acc[nt] = __builtin_amdgcn_mfma_f32_16x16x32_bf16(a, bb, acc[nt], 0, 0, 0);
    }
  }
  if (!FINAL) {
#pragma unroll
    for (int nt = 0; nt < 8; ++nt) {
      int ch = nt * 16 + cl;
      float bv = bia[ch];
      float v0 = acc[nt][0] + bv, v1 = acc[nt][1] + bv, v2 = acc[nt][2] + bv, v3 = acc[nt][3] + bv;
      float s1 = (v0 + v1) + (v2 + v3);
      float s2 = (v0 * v0 + v1 * v1) + (v2 * v2 + v3 * v3);
      s1 += __shfl_xor(s1, 16); s1 += __shfl_xor(s1, 32);
      s2 += __shfl_xor(s2, 16); s2 += __shfl_xor(s2, 32);
      if (rg == 0) { sred[wid][0][ch] = s1; sred[wid][1][ch] = s2; }
    }
    __syncthreads();
    {
      int ch = t & 127, wh = t >> 7;
      float v = sred[0][wh][ch] + sred[1][wh][ch] + sred[2][wh][ch] + sred[3][wh][ch];
      part[(size_t)blk * 256 + ch * 2 + wh] = v;
    }
  } else {
#pragma unroll
    for (int nt = 0; nt < 8; ++nt) {
      int ch = nt * 16 + cl;
      float bv = bia[ch];
      float a0 = fmaxf(0.f, s3c[ch] * (acc[nt][0] + bv) + s3h[ch]);
      float a1 = fmaxf(0.f, s3c[ch] * (acc[nt][1] + bv) + s3h[ch]);
      float a2 = fmaxf(0.f, s3c[ch] * (acc[nt][2] + bv) + s3h[ch]);
      float a3 = fmaxf(0.f, s3c[ch] * (acc[nt][3] + bv) + s3h[ch]);
      float m = fmaxf(fmaxf(a0, a1), fmaxf(a2, a3));
      m = fmaxf(m, __shfl_xor(m, 16));
      m = fmaxf(m, __shfl_xor(m, 32));
      if (rg == 0) sred[wid][0][ch] = m;
    }
    __syncthreads();
    {
      int qq = t >> 7, ch = t & 127;
      float v = fmaxf(sred[qq * 2][0][ch], sred[qq * 2 + 1][0][ch]);
      kmaxb[((size_t)blk * 2 + qq) * 128 + ch] = v;
    }
  }
}

// ---------------- transpose kmax (B,S,128) -> out1 (B,128,S)
__global__ __launch_bounds__(256) void k_tr(const float* __restrict__ kmaxb,
                                            float* __restrict__ out1) {
  __shared__ float tile[32][33];
  int t = threadIdx.x, blk = blockIdx.x;
  int b = blk >> 7, rem = blk & 127, ct = rem >> 5, st = rem & 31;
  int c0 = ct * 32, s0 = st * 32;
#pragma unroll
  for (int p = 0; p < 4; ++p)
    tile[(t >> 5) + p * 8][t & 31] =
        kmaxb[(size_t)b * 131072 + (size_t)(s0 + (t >> 5) + p * 8) * 128 + c0 + (t & 31)];
  __syncthreads();
#pragma unroll
  for (int p = 0; p < 4; ++p) {
    int c = c0 + (t >> 5) + p * 8;
    int s = s0 + (t & 31);
    out1[(size_t)b * 131072 + (size_t)c * 1024 + s] = tile[t & 31][(t >> 5) + p * 8];
  }
}

extern "C" void kernel_launch(void* const* d_in, const int* in_sizes, int n_in,
                              void* d_out, int out_size, void* d_ws, size_t ws_size,
                              hipStream_t stream) {
  (void)in_sizes; (void)n_in; (void)out_size;
  const float* xyz    = (const float*)d_in[0];
  const float* points = (const float*)d_in[1];
  const float* w0  = (const float*)d_in[2];
  const float* b0  = (const float*)d_in[3];
  const float* g0  = (const float*)d_in[4];
  const float* be0 = (const float*)d_in[5];
  const float* w1  = (const float*)d_in[6];
  const float* b1  = (const float*)d_in[7];
  const float* g1  = (const float*)d_in[8];
  const float* be1 = (const float*)d_in[9];
  const float* w2  = (const float*)d_in[10];
  const float* b2  = (const float*)d_in[11];
  const float* g2  = (const float*)d_in[12];
  const float* be2 = (const float*)d_in[13];
  float* out  = (float*)d_out;
  float* out0 = out;
  float* out1 = out + 49152;
  float* out2 = out + 49152 + 2097152;
  char* ws = (char*)d_ws;
  const size_t OFF_PT   = 0;         // 16*4096*64*2 = 8388608
  const size_t OFF_XYZ4 = 8388608;   // 1048576
  const size_t OFF_NQ4  = 9437184;   // 262144
  const size_t OFF_FPS  = 9699328;   // 65536
  const size_t OFF_BALL = 9764864;   // 2097152
  const size_t OFF_XBUF = 11862016;  // 67108864
  const size_t OFF_PART = 78970880;  // 8388608
  const size_t OFF_SC   = 87359488;  // 4096
  const size_t OFF_KMAX = 87363584;  // 8388608
  const size_t NEED     = 95752192;
  if (ws_size < NEED) return;
  unsigned short* pT   = (unsigned short*)(ws + OFF_PT);
  float4* xyz4 = (float4*)(ws + OFF_XYZ4);
  float4* nq4  = (float4*)(ws + OFF_NQ4);
  int* fpsidx  = (int*)(ws + OFF_FPS);
  int* ballidx = (int*)(ws + OFF_BALL);
  unsigned short* xbuf = (unsigned short*)(ws + OFF_XBUF);
  float* part  = (float*)(ws + OFF_PART);
  float* scb   = (float*)(ws + OFF_SC);
  float *sc1 = scb, *sh1 = scb + 128, *sc2 = scb + 256, *sh2 = scb + 384,
        *sc3 = scb + 512, *sh3 = scb + 640;
  float* kmaxb = (float*)(ws + OFF_KMAX);

  k_prep<<<1024, 256, 0, stream>>>(points, xyz, pT, xyz4);
  k_fps<<<16, 256, 0, stream>>>(xyz, out0, out2, fpsidx, nq4);
  k_ball<<<1024, 256, 0, stream>>>(xyz4, fpsidx, ballidx);
  k_gemm1<<<8192, 256, 0, stream>>>(pT, xyz4, nq4, ballidx, w0, b0, xbuf, part);
  k_red<<<64, 256, 0, stream>>>(part, 8192, 64, g0, be0, sc1, sh1);
  k_gemm2<<<8192, 256, 0, stream>>>(xbuf, w1, b1, sc1, sh1, part);
  k_red<<<64, 256, 0, stream>>>(part, 8192, 64, g1, be1, sc2, sh2);
  k_gemm3<false><<<8192, 256, 0, stream>>>(xbuf, w2, b2, sc2, sh2, nullptr, nullptr, part, nullptr);
  k_red<<<128, 256, 0, stream>>>(part, 8192, 128, g2, be2, sc3, sh3);
  k_gemm3<true><<<8192, 256, 0, stream>>>(xbuf, w2, b2, sc2, sh2, sc3, sh3, nullptr, kmaxb);
  k_tr<<<2048, 256, 0, stream>>>(kmaxb, out1);
}